// Round 7
// baseline (20.380 us; speedup 1.0000x reference)
//
#include <hip/hip_runtime.h>

#define PAD_VAL 9999.0f
constexpr int BATCH = 8;
constexpr int NS = 1024;      // support rows
constexpr int NF = 32;        // features
constexpr int NQUANT = 999;   // quantile count
constexpr int NT = 512;       // threads per block (8 waves -> 2 waves/SIMD)
constexpr int EPL = 2;        // elements per lane (1024 / 512)

// ---------------- prep: transpose xs/xq to [arr][b][f][row] + mask pack ----------------
__global__ __launch_bounds__(256) void prep(const float* __restrict__ xs,
                                            const float* __restrict__ xq,
                                            const unsigned char* __restrict__ mraw,
                                            float* __restrict__ xT,
                                            unsigned char* __restrict__ mbits,
                                            float* __restrict__ seqlen) {
    const int beta = blockIdx.x;
    const int t = threadIdx.x;
    if (beta < 128) {
        // transpose one 128-row x 32-feat tile. XCD-aligned: batch = beta&7.
        __shared__ float lds[32][129];
        const int b = beta & 7;
        const int arr = (beta >> 3) & 1;
        const int tile = beta >> 4;                   // 0..7
        const float* src = (arr ? xq : xs) + ((size_t)b * NS + tile * 128) * NF;
        float* dst = xT + (size_t)arr * (BATCH * NF * NS) + (size_t)b * NF * NS + tile * 128;
        const float4* s4 = (const float4*)src;
        #pragma unroll
        for (int s = 0; s < 4; s++) {
            int e = t + s * 256;                      // 0..1023 float4s (16KB tile)
            float4 d = s4[e];
            int row = e >> 3, f4 = e & 7;
            lds[f4 * 4 + 0][row] = d.x; lds[f4 * 4 + 1][row] = d.y;
            lds[f4 * 4 + 2][row] = d.z; lds[f4 * 4 + 3][row] = d.w;
        }
        __syncthreads();
        #pragma unroll
        for (int s = 0; s < 16; s++) {
            int e = t + s * 256;                      // 0..4095 scalars
            int f = e >> 7, row = e & 127;
            dst[f * NS + row] = lds[f][row];          // coalesced 256B runs per wave
        }
    } else {
        // mask block for batch m: mode detect (first 8KB), pack 1 bit/row, seq_len
        const int m = beta - 128;
        __shared__ int flags[2];
        __shared__ int cnt_sh;
        if (t == 0) { flags[0] = 0; flags[1] = 0; cnt_sh = 0; }
        __syncthreads();
        {
            int l3f = 0, loff = 0;
            uint4 d0 = ((const uint4*)mraw)[t * 2];
            uint4 d1 = ((const uint4*)mraw)[t * 2 + 1];
            unsigned w[8] = {d0.x, d0.y, d0.z, d0.w, d1.x, d1.y, d1.z, d1.w};
            #pragma unroll
            for (int c = 0; c < 8; c++) {
                if ((w[c] >> 24) == 0x3fu) l3f = 1;          // f32 1.0f top byte
                if ((w[c] & 0xFFFFFF00u) != 0u) loff = 1;    // nonzero high bytes
            }
            if (__ballot(l3f)  && (t & 63) == 0) atomicOr(&flags[0], 1);
            if (__ballot(loff) && (t & 63) == 0) atomicOr(&flags[1], 1);
        }
        __syncthreads();
        const int mode = flags[0] ? 2 : (flags[1] ? 1 : 0);  // 2=f32 1=byte 0=int32
        if (t < 128) {
            unsigned byte = 0;
            #pragma unroll
            for (int r = 0; r < 8; r++) {
                int idx = m * NS + t * 8 + r;
                int mm;
                if (mode == 1)      mm = (mraw[idx] != 0);
                else if (mode == 0) mm = (((const int*)mraw)[idx] != 0);
                else                mm = (((const float*)mraw)[idx] != 0.0f);
                byte |= (mm ? 1u : 0u) << r;
            }
            mbits[m * 128 + t] = (unsigned char)byte;
            atomicAdd(&cnt_sh, 8 - __popc(byte));
        }
        __syncthreads();
        if (t == 0) seqlen[m] = (float)cnt_sh;
    }
}

// ---------------- bitonic network (register/shfl + double-buffered LDS) ----------------
template<int K, int J, int P>
__device__ __forceinline__ void bstage(float (&v)[EPL], const int t,
                                       float* bufA, float* bufB) {
    if constexpr (J >= 64 * EPL) {            // J = 128/256/512: cross-wave
        float* buf = (P & 1) ? bufB : bufA;   // alternate buffers -> 1 barrier/stage
        *(float2*)(buf + t * EPL) = *(const float2*)v;
        __syncthreads();
        float o[EPL] __attribute__((aligned(8)));
        *(float2*)o = *(const float2*)(buf + ((t * EPL) ^ J));
        const bool keepmin = ((((t * EPL) & J) == 0) == (((t * EPL) & K) == 0));
        #pragma unroll
        for (int r = 0; r < EPL; r++)
            v[r] = keepmin ? fminf(v[r], o[r]) : fmaxf(v[r], o[r]);
        if constexpr (J > 1) bstage<K, J / 2, P + 1>(v, t, bufA, bufB);
    } else if constexpr (J >= EPL) {          // J = 2..64: lane xor m = J/2 (<=32)
        constexpr int m = J / EPL;
        const bool keepmin = ((((t * EPL) & J) == 0) == (((t * EPL) & K) == 0));
        #pragma unroll
        for (int r = 0; r < EPL; r++) {
            float o = __shfl_xor(v[r], m, 64);
            v[r] = keepmin ? fminf(v[r], o) : fmaxf(v[r], o);
        }
        if constexpr (J > 1) bstage<K, J / 2, P>(v, t, bufA, bufB);
    } else {                                   // J = 1: in-register swap
        const bool dir = (((t * EPL) & K) == 0);
        float a = v[0], c = v[1];
        float mn = fminf(a, c), mx = fmaxf(a, c);
        v[0] = dir ? mn : mx;
        v[1] = dir ? mx : mn;
    }
}

template<int K, int P>
__device__ __forceinline__ void bsort(float (&v)[EPL], const int t,
                                      float* bufA, float* bufB) {
    constexpr int nlds = (K <= 128) ? 0 : (K == 256 ? 1 : (K == 512 ? 2 : 3));
    bstage<K, K / 2, P>(v, t, bufA, bufB);
    if constexpr (K < NS) bsort<K * 2, P + nlds>(v, t, bufA, bufB);
}

// ---------------- fused: sort + quantiles + bucketize + stats + outputs ----------------
__global__ __launch_bounds__(NT) void fused(const float* __restrict__ xT,
                                            const unsigned char* __restrict__ mbits,
                                            const float* __restrict__ seqlen,
                                            float* __restrict__ outS,
                                            float* __restrict__ outQ) {
    __shared__ float buf[NS];      // sort exchange A + sorted column
    __shared__ float squant[NS];   // sort exchange B, then quantile table
    __shared__ float rstat[16];

    const int t = threadIdx.x;
    const int lane = t & 63, w = t >> 6;
    // XCD-aware: bid%8 = XCD = batch (matches prep's writer XCD)
    const int b = blockIdx.x & 7, f = blockIdx.x >> 3;

    // ---- all loads issued up front: coalesced column loads + mask byte + seqlen ----
    const float* xcol = xT + ((size_t)b * NF + f) * NS;
    const float* qcol = xT + (size_t)BATCH * NF * NS + ((size_t)b * NF + f) * NS;
    float2 xv2 = *(const float2*)(xcol + t * EPL);
    float2 qv2 = *(const float2*)(qcol + t * EPL);
    const unsigned mbyte = mbits[b * 128 + (t >> 2)];
    const float sl = seqlen[b];
    const unsigned mkbits = (mbyte >> ((t & 3) * 2)) & 3u;

    const float xv[EPL] = {xv2.x, xv2.y};
    const float qv[EPL] = {qv2.x, qv2.y};
    float v[EPL] __attribute__((aligned(8)));
    v[0] = (mkbits & 1u) ? PAD_VAL : xv[0];
    v[1] = (mkbits & 2u) ? PAD_VAL : xv[1];

    // ---- bitonic sort (register/shfl + 6 double-buffered LDS stages) ----
    bsort<2, 0>(v, t, buf, squant);

    // sorted -> buf. Safe without a pre-barrier: last LDS stage (P5) used squant,
    // and its barrier ordered all earlier buf readers before this point.
    *(float2*)(buf + t * EPL) = *(const float2*)v;
    __syncthreads();

    // ---- quantiles (exact reference f32 arithmetic) -> squant ----
    #pragma unroll
    for (int s = 0; s < EPL; s++) {
        int qi = t + s * NT;
        if (qi < NQUANT) {
            float q = (float)(qi + 1) / 1000.0f;
            float idxf = q * (float)(NS - 1);
            int lo = (int)idxf;
            int hi = min(lo + 1, NS - 1);
            float frac = idxf - (float)lo;
            float a = buf[lo], c = buf[hi];
            squant[qi] = a + frac * (c - a);
        }
    }
    __syncthreads();

    // ---- support + query searches, interleaved (4 streams of ILP) ----
    int pos[EPL], posq[EPL];
    #pragma unroll
    for (int r = 0; r < EPL; r++) { pos[r] = 0; posq[r] = 0; }
    #pragma unroll
    for (int step = 512; step > 0; step >>= 1) {
        #pragma unroll
        for (int r = 0; r < EPL; r++) {
            int np = pos[r] + step;
            if (np <= NQUANT && squant[np - 1] <= xv[r]) pos[r] = np;
            int nq = posq[r] + step;
            if (nq <= NQUANT && squant[nq - 1] <= qv[r]) posq[r] = nq;
        }
    }

    // ---- stats over support buckets ----
    float sum = 0.0f, sumsq = 0.0f;
    float vs[EPL];
    #pragma unroll
    for (int r = 0; r < EPL; r++) {
        float vv = ((mkbits >> r) & 1u) ? 0.0f : (float)pos[r] / sl;
        vs[r] = vv;
        sum += vv; sumsq += vv * vv;
    }
    #pragma unroll
    for (int o = 1; o < 64; o <<= 1) {
        sum   += __shfl_xor(sum, o, 64);
        sumsq += __shfl_xor(sumsq, o, 64);
    }
    if (lane == 0) { rstat[w] = sum; rstat[8 + w] = sumsq; }
    __syncthreads();
    float S = 0.0f, Q = 0.0f;
    #pragma unroll
    for (int i = 0; i < 8; i++) { S += rstat[i]; Q += rstat[8 + i]; }
    const float mean = S / sl;
    const float var = fmaxf(Q / sl - mean * mean, 0.0f);
    const float istd = (var > 0.0f) ? (1.0f / sqrtf(var)) : 0.0f;

    // ---- outputs (row-major, strided stores; fire-and-forget) ----
    float* oscol = outS + (size_t)(b * NS) * NF + f;
    float* oqcol = outQ + (size_t)(b * NS) * NF + f;
    #pragma unroll
    for (int r = 0; r < EPL; r++)
        oscol[(t * EPL + r) * NF] = ((mkbits >> r) & 1u) ? 0.0f : (vs[r] - mean) * istd;
    #pragma unroll
    for (int r = 0; r < EPL; r++)
        oqcol[(t * EPL + r) * NF] = ((float)posq[r] / sl - mean) * istd;
}

extern "C" void kernel_launch(void* const* d_in, const int* in_sizes, int n_in,
                              void* d_out, int out_size, void* d_ws, size_t ws_size,
                              hipStream_t stream) {
    const float* xs = (const float*)d_in[0];
    const float* xq = (const float*)d_in[1];
    const unsigned char* mraw = (const unsigned char*)d_in[2];
    float* out = (float*)d_out;

    // ws layout: xsT [8][32][1024] f32 | xqT same | mask bytes (8*128) | seqlen f32[8]
    float* xT = (float*)d_ws;
    unsigned char* mbits = (unsigned char*)d_ws + 2u * BATCH * NF * NS * 4u;
    float* seqlen = (float*)((char*)d_ws + 2u * BATCH * NF * NS * 4u + 4096u);

    prep<<<136, 256, 0, stream>>>(xs, xq, mraw, xT, mbits, seqlen);
    fused<<<BATCH * NF, NT, 0, stream>>>(xT, mbits, seqlen,
                                         out, out + BATCH * NS * NF);
}

// Round 8
// 17.196 us; speedup vs baseline: 1.1851x; 1.1851x over previous
//
#include <hip/hip_runtime.h>

#define PAD_VAL 9999.0f
constexpr int BATCH = 8;
constexpr int NS = 1024;      // support rows
constexpr int NF = 32;        // features
constexpr int NQUANT = 999;   // quantile count
constexpr int NT = 512;       // threads per block (8 waves -> 2 waves/SIMD)
constexpr int EPL = 2;        // elements per lane (1024 / 512)

// ---------------- bitonic network (register/shfl + double-buffered LDS) ----------------
// LDS stage numbering P: K=256 -> P=0 ; K=512 -> P=1,2 ; K=1024 -> P=3,4,5.
// Consecutive LDS stages alternate buffers -> one barrier per stage suffices.
template<int K, int J, int P>
__device__ __forceinline__ void bstage(float (&v)[EPL], const int t,
                                       float* bufA, float* bufB) {
    if constexpr (J >= 64 * EPL) {            // J = 128/256/512: cross-wave
        float* buf = (P & 1) ? bufB : bufA;
        *(float2*)(buf + t * EPL) = *(const float2*)v;
        __syncthreads();
        float o[EPL] __attribute__((aligned(8)));
        *(float2*)o = *(const float2*)(buf + ((t * EPL) ^ J));
        const bool keepmin = ((((t * EPL) & J) == 0) == (((t * EPL) & K) == 0));
        #pragma unroll
        for (int r = 0; r < EPL; r++)
            v[r] = keepmin ? fminf(v[r], o[r]) : fmaxf(v[r], o[r]);
        if constexpr (J > 1) bstage<K, J / 2, P + 1>(v, t, bufA, bufB);
    } else if constexpr (J >= EPL) {          // J = 2..64: lane xor m = J/2 (<=32)
        constexpr int m = J / EPL;
        const bool keepmin = ((((t * EPL) & J) == 0) == (((t * EPL) & K) == 0));
        #pragma unroll
        for (int r = 0; r < EPL; r++) {
            float o = __shfl_xor(v[r], m, 64);
            v[r] = keepmin ? fminf(v[r], o) : fmaxf(v[r], o);
        }
        if constexpr (J > 1) bstage<K, J / 2, P>(v, t, bufA, bufB);
    } else {                                   // J = 1: in-register swap
        const bool dir = (((t * EPL) & K) == 0);
        float a = v[0], c = v[1];
        float mn = fminf(a, c), mx = fmaxf(a, c);
        v[0] = dir ? mn : mx;
        v[1] = dir ? mx : mn;
    }
}

template<int K, int P>
__device__ __forceinline__ void bsort(float (&v)[EPL], const int t,
                                      float* bufA, float* bufB) {
    constexpr int nlds = (K <= 128) ? 0 : (K == 256 ? 1 : (K == 512 ? 2 : 3));
    bstage<K, K / 2, P>(v, t, bufA, bufB);
    if constexpr (K < NS) bsort<K * 2, P + nlds>(v, t, bufA, bufB);
}

__global__ __launch_bounds__(NT) void fused(const float* __restrict__ xs,
                                            const float* __restrict__ xq,
                                            const unsigned char* __restrict__ mraw,
                                            float* __restrict__ outS,
                                            float* __restrict__ outQ) {
    __shared__ float buf[NS];      // sort exchange A + sorted column
    __shared__ float squant[NS];   // sort exchange B, then quantile table
    __shared__ int   wcnt[8];
    __shared__ float rstat[16];

    const int t = threadIdx.x;
    const int lane = t & 63, w = t >> 6;
    // XCD-aware: bid%8 = XCD = batch -> each XCD serves one batch from its L2
    const int b = blockIdx.x & 7, f = blockIdx.x >> 3;

    // ---- 1. strided column gathers issued FIRST (latency overlaps mask phase) ----
    const float* xscol = xs + (size_t)(b * NS) * NF + f;
    const float* xqcol = xq + (size_t)(b * NS) * NF + f;
    float xv[EPL], qv[EPL];
    #pragma unroll
    for (int r = 0; r < EPL; r++) xv[r] = xscol[(t * EPL + r) * NF];
    #pragma unroll
    for (int r = 0; r < EPL; r++) qv[r] = xqcol[(t * EPL + r) * NF];

    // ---- 2. per-wave mask-layout detect (1 KiB window/wave; no barrier, no atomic) ----
    // byte-bool: random 0/1 bytes -> some nonzero byte at pos%4!=0 (certain).
    // f32: 1.0f -> top byte 0x3f somewhere. int32 0/1: neither pattern.
    uint4 dm = ((const uint4*)mraw)[t];
    int l3f  = ((dm.x >> 24) == 0x3fu) | ((dm.y >> 24) == 0x3fu) |
               ((dm.z >> 24) == 0x3fu) | ((dm.w >> 24) == 0x3fu);
    int loff = ((dm.x | dm.y | dm.z | dm.w) & 0xFFFFFF00u) != 0u;
    const int mode = __ballot(l3f) ? 2 : (__ballot(loff) ? 1 : 0); // 2=f32 1=byte 0=int32

    // ---- 3. own 2 mask bits + per-wave seq_len partial ----
    unsigned mkbits;
    if (mode == 1) {
        unsigned short mw = *(const unsigned short*)(mraw + b * NS + t * EPL);
        mkbits = ((mw & 0xffu) ? 1u : 0u) | ((mw >> 8) ? 2u : 0u);
    } else if (mode == 0) {
        uint2 d = ((const uint2*)mraw)[b * (NS / 2) + t];
        mkbits = (d.x != 0) | ((d.y != 0) << 1);
    } else {
        float2 d = ((const float2*)mraw)[b * (NS / 2) + t];
        mkbits = (d.x != 0.0f) | ((d.y != 0.0f) << 1);
    }
    {
        int cnt = EPL - __popc(mkbits);
        #pragma unroll
        for (int o = 1; o < 64; o <<= 1) cnt += __shfl_xor(cnt, o, 64);
        if (lane == 0) wcnt[w] = cnt;      // ordered by the sort's first barrier
    }

    float v[EPL] __attribute__((aligned(8)));
    v[0] = (mkbits & 1u) ? PAD_VAL : xv[0];
    v[1] = (mkbits & 2u) ? PAD_VAL : xv[1];

    // ---- 4. bitonic sort (register/shfl + 6 double-buffered LDS stages) ----
    bsort<2, 0>(v, t, buf, squant);

    // sorted -> buf. No pre-barrier needed: last LDS stage (P=5) used squant and
    // its barrier ordered all earlier buf readers (each thread's P=4 buf read is
    // data-depended by its P=5 write, which precedes that barrier).
    *(float2*)(buf + t * EPL) = *(const float2*)v;
    __syncthreads();

    const float sl = (float)(wcnt[0] + wcnt[1] + wcnt[2] + wcnt[3] +
                             wcnt[4] + wcnt[5] + wcnt[6] + wcnt[7]);

    // ---- 5. quantiles (exact reference f32 arithmetic) -> squant ----
    #pragma unroll
    for (int s = 0; s < EPL; s++) {
        int qi = t + s * NT;
        if (qi < NQUANT) {
            float q = (float)(qi + 1) / 1000.0f;
            float idxf = q * (float)(NS - 1);
            int lo = (int)idxf;
            int hi = min(lo + 1, NS - 1);
            float frac = idxf - (float)lo;
            float a = buf[lo], c = buf[hi];
            squant[qi] = a + frac * (c - a);
        }
    }
    __syncthreads();

    // ---- 6. support + query searches, interleaved (4 streams of ILP) ----
    int pos[EPL], posq[EPL];
    #pragma unroll
    for (int r = 0; r < EPL; r++) { pos[r] = 0; posq[r] = 0; }
    #pragma unroll
    for (int step = 512; step > 0; step >>= 1) {
        #pragma unroll
        for (int r = 0; r < EPL; r++) {
            int np = pos[r] + step;
            if (np <= NQUANT && squant[np - 1] <= xv[r]) pos[r] = np;
            int nq = posq[r] + step;
            if (nq <= NQUANT && squant[nq - 1] <= qv[r]) posq[r] = nq;
        }
    }

    // ---- 7. stats over support buckets ----
    float sum = 0.0f, sumsq = 0.0f;
    float vs[EPL];
    #pragma unroll
    for (int r = 0; r < EPL; r++) {
        float vv = ((mkbits >> r) & 1u) ? 0.0f : (float)pos[r] / sl;
        vs[r] = vv;
        sum += vv; sumsq += vv * vv;
    }
    #pragma unroll
    for (int o = 1; o < 64; o <<= 1) {
        sum   += __shfl_xor(sum, o, 64);
        sumsq += __shfl_xor(sumsq, o, 64);
    }
    if (lane == 0) { rstat[w] = sum; rstat[8 + w] = sumsq; }
    __syncthreads();
    float S = 0.0f, Q = 0.0f;
    #pragma unroll
    for (int i = 0; i < 8; i++) { S += rstat[i]; Q += rstat[8 + i]; }
    const float mean = S / sl;
    const float var = fmaxf(Q / sl - mean * mean, 0.0f);
    const float istd = (var > 0.0f) ? (1.0f / sqrtf(var)) : 0.0f;

    // ---- 8. outputs (row-major strided stores; fire-and-forget tail) ----
    float* oscol = outS + (size_t)(b * NS) * NF + f;
    float* oqcol = outQ + (size_t)(b * NS) * NF + f;
    #pragma unroll
    for (int r = 0; r < EPL; r++)
        oscol[(t * EPL + r) * NF] = ((mkbits >> r) & 1u) ? 0.0f : (vs[r] - mean) * istd;
    #pragma unroll
    for (int r = 0; r < EPL; r++)
        oqcol[(t * EPL + r) * NF] = ((float)posq[r] / sl - mean) * istd;
}

extern "C" void kernel_launch(void* const* d_in, const int* in_sizes, int n_in,
                              void* d_out, int out_size, void* d_ws, size_t ws_size,
                              hipStream_t stream) {
    const float* xs = (const float*)d_in[0];
    const float* xq = (const float*)d_in[1];
    const unsigned char* mraw = (const unsigned char*)d_in[2];
    float* out = (float*)d_out;

    fused<<<BATCH * NF, NT, 0, stream>>>(xs, xq, mraw,
                                         out, out + BATCH * NS * NF);
}